// Round 6
// baseline (135.132 us; speedup 1.0000x reference)
//
#include <hip/hip_runtime.h>
#include <stdint.h>

// RBF kernel regression: out = exp(-gamma*d2(Xq,Xt)) @ alpha
// out[m] = ea[m] * sum_n w[n] * 2^( S[m][n] ),  S = (2*gamma*log2e*Xq).Xt^T
//
// R16: LDS-B super-step pipeline (R11 structure) with the allocator finally
// given headroom: __launch_bounds__(256,1). R15 forensics: R11's VGPR=108 <
// afrag's 128 proves every prior LDS variant SANK the A-fragment loads into
// the loop (A re-streamed via TA each super-step) -> 59us. With (256,1) the
// allocator can hold afrag resident (~233 VGPR working set), runtime
// occupancy still 2 blocks/CU (2048/233), same as the register-ping-pong
// baseline -- but B now multicasts through the LDS pipe (one global load
// per CU instead of 8): TA ~0.75MB/CU, LDS ~2.5MB/CU, MFMA 39.7K cyc ->
// MFMA-bound on paper. Pipeline: 4 LDS buffers, 2 tiles/super-step; loads
// for tiles 2s+4,2s+5 issued at top of s, ds_written at top of s+1, computed
// in s+2 -> barrier's vmcnt drain covered by a full super-step.
// Kill-signal: VGPR<=128 or scratch traffic -> abandon LDS permanently.
// R14 lesson: no s_setprio (splits sched regions -> spill). R0 swizzle
// restored (8 consecutive slots share nx -> XCD-L2 B locality).

#define MM 8192
#define NN 8192
#define DD 256
#define GAMMA (1.0f/256.0f)
#define LOG2E 1.44269504088896340736f
#define SCALE_A (2.0f*GAMMA*LOG2E)
#define NEG_G_LOG2E (-GAMMA*LOG2E)

#define NSPLIT 16
#define NPB (NN/NSPLIT)     // 512 cols per block
#define NT_PER (NPB/16)     // 32 column-tiles of 16

typedef __bf16 bf16x8 __attribute__((ext_vector_type(8)));
typedef float  f32x4  __attribute__((ext_vector_type(4)));

// ws: [0,4MB) A frag-linear; [4MB,8MB) B frag-linear; [8MB,+32K) w; [+32K] ea
#define A_OFF  ((size_t)0)
#define B_OFF  ((size_t)4 << 20)
#define W_OFF  ((size_t)8 << 20)
#define EA_OFF (((size_t)8 << 20) + 32768)

__device__ __forceinline__ unsigned short f2bf(float f) {  // RNE f32->bf16
  union { float f; uint32_t u; } x; x.f = f;
  uint32_t u = x.u;
  u += 0x7FFFu + ((u >> 16) & 1u);
  return (unsigned short)(u >> 16);
}
__device__ __forceinline__ uint32_t pack2(float a, float b) {
  return (uint32_t)f2bf(a) | ((uint32_t)f2bf(b) << 16);
}

// One wave per 16-row/col tile. Fragment-linear pack: tile t, round r, lane l
// writes dst + t*8192 + r*1024 + l*16 holding k-granule g=r*4+(l>>4) of
// row/col n=t*16+(l&15) — exactly the mfma_16x16x32 A/B operand layout.
__global__ __launch_bounds__(256) void prep_kernel(
    const float* __restrict__ Xq, const float* __restrict__ Xt,
    const float* __restrict__ alpha,
    char* __restrict__ Amat, char* __restrict__ Bmat,
    float* __restrict__ w, float* __restrict__ ea, float* __restrict__ out)
{
  // zero the output (rbf_main accumulates into it with atomics)
  const int gi = blockIdx.x * 256 + threadIdx.x;
  if (gi < MM) out[gi] = 0.f;

  const int lane = threadIdx.x & 63;
  const int gw = blockIdx.x * 4 + (threadIdx.x >> 6);  // 0..1023
  const bool isA = gw < 512;
  const int t = isA ? gw : gw - 512;
  const float* __restrict__ src = isA ? Xq : Xt;
  char* __restrict__ dst = isA ? Amat : Bmat;
  const float sc = isA ? SCALE_A : 1.0f;
  const int n = t * 16 + (lane & 15);
  float ss = 0.f;
#pragma unroll
  for (int r = 0; r < 8; ++r) {
    const int gg = r * 4 + (lane >> 4);
    const float* p = src + (size_t)n * DD + gg * 8;
    const float4 f0 = *(const float4*)p;
    const float4 f1 = *(const float4*)(p + 4);
    ss += f0.x*f0.x + f0.y*f0.y + f0.z*f0.z + f0.w*f0.w
        + f1.x*f1.x + f1.y*f1.y + f1.z*f1.z + f1.w*f1.w;
    uint4 pk;
    pk.x = pack2(f0.x * sc, f0.y * sc); pk.y = pack2(f0.z * sc, f0.w * sc);
    pk.z = pack2(f1.x * sc, f1.y * sc); pk.w = pack2(f1.z * sc, f1.w * sc);
    *(uint4*)(dst + (size_t)t * 8192 + r * 1024 + lane * 16) = pk;
  }
  ss += __shfl_xor(ss, 16, 64);   // reduce the 4 lanes holding col n
  ss += __shfl_xor(ss, 32, 64);
  if (lane < 16) {
    if (isA) ea[n] = __builtin_amdgcn_exp2f(NEG_G_LOG2E * ss);
    else     w[n]  = alpha[n] * __builtin_amdgcn_exp2f(NEG_G_LOG2E * ss);
  }
}

__global__ __launch_bounds__(256, 1) void rbf_main(
    const char* __restrict__ Amat, const char* __restrict__ Bmat,
    const float* __restrict__ w, const float* __restrict__ ea,
    float* __restrict__ out)
{
  __shared__ float lds_w[NPB];        // 2 KB
  __shared__ uint4 lds_b[4][512];     // 4 B-tile buffers x 8 KB = 32 KB

  const int tid  = threadIdx.x;
  const int wave = tid >> 6, lane = tid & 63;
  const int quad = lane >> 4, l16 = lane & 15;

  // R0 swizzle: 512 blocks = 32 my x 16 nx; XCD b&7 gets 8 my x 8 nx;
  // 8 consecutive slots share nx (B-panel locality in the XCD's L2).
  const int b    = blockIdx.x;
  const int xcd  = b & 7, slot = b >> 3;             // slot 0..63
  const int my   = (xcd & 3) * 8 + (slot & 7);       // 0..31 (256 rows each)
  const int nx   = (xcd >> 2) * 8 + (slot >> 3);     // 0..15
  const int mt0    = my * 16 + wave * 4;             // 4 mtiles = 64 rows/wave
  const int nt0    = nx * NT_PER;
  const int nbase0 = nx * NPB;

  const uint4* __restrict__ Bm4 = (const uint4*)Bmat;  // tile = 512 uint4

  // register staging: each thread carries 2 uint4 per tile, 2 tiles/super-step
  uint4 st[4];
  auto stageL = [&](int t0) {      // issue global loads for tiles t0, t0+1
#pragma unroll
    for (int i = 0; i < 2; ++i) {
      st[i*2+0] = Bm4[(size_t)(nt0 + t0 + i) * 512 + tid];
      st[i*2+1] = Bm4[(size_t)(nt0 + t0 + i) * 512 + 256 + tid];
    }
  };
  auto stageW = [&](int t0) {      // ds_write tiles t0, t0+1 into buffers
#pragma unroll
    for (int i = 0; i < 2; ++i) {
      lds_b[(t0 + i) & 3][tid]       = st[i*2+0];
      lds_b[(t0 + i) & 3][256 + tid] = st[i*2+1];
    }
  };

  // prologue: oldest-first issue order so vmcnt retires in order
  stageL(0);                                    // tiles 0,1 -> st
  {
    const float2 wv2 = *(const float2*)(w + nbase0 + tid * 2);
    lds_w[tid * 2]     = wv2.x;
    lds_w[tid * 2 + 1] = wv2.y;
  }
  // A fragments register-resident for full K=256: 4 mtiles x 8 kc = 128 VGPR
  bf16x8 afrag[4][8];
#pragma unroll
  for (int rt = 0; rt < 4; ++rt)
#pragma unroll
    for (int kc = 0; kc < 8; ++kc) {
      union { uint4 u; bf16x8 v; } cv;
      cv.u = *(const uint4*)(Amat + (size_t)(mt0 + rt) * 8192 + kc * 1024 + lane * 16);
      afrag[rt][kc] = cv.v;
    }
  stageW(0);                                    // tiles 0,1 -> buf0,buf1
  stageL(2);                                    // tiles 2,3 in flight
  __syncthreads();                              // buf0,buf1 + lds_w visible

  float outacc[4][4] = {{0,0,0,0},{0,0,0,0},{0,0,0,0},{0,0,0,0}};
  const f32x4 fzero = {0.f, 0.f, 0.f, 0.f};

  // 16 super-steps of 2 tiles. Invariant at top of s: bufs for tiles 2s,2s+1
  // barrier-published; loads for 2s+2,2s+3 landed in st (full super-step of
  // flight time). Writes go to the buffers freed by super-step s-1.
  for (int s = 0; s < NT_PER / 2; ++s) {
    if (s < NT_PER / 2 - 1) stageW(2 * s + 2);  // bufs (2s+2)&3,(2s+3)&3
    if (s < NT_PER / 2 - 2) stageL(2 * s + 4);  // next loads, full ss to land
#pragma unroll
    for (int half = 0; half < 2; ++half) {
      const int ct = 2 * s + half;
      const uint4* bp = &lds_b[ct & 3][0];
      bf16x8 bf[8];
#pragma unroll
      for (int kc = 0; kc < 8; ++kc) {         // 8x ds_read_b128, batched
        union { uint4 u; bf16x8 v; } cv;
        cv.u = bp[kc * 64 + lane];
        bf[kc] = cv.v;
      }
      f32x4 acc[4];
#pragma unroll
      for (int rt = 0; rt < 4; ++rt) acc[rt] = fzero;
#pragma unroll
      for (int kc = 0; kc < 8; ++kc)
#pragma unroll
        for (int rt = 0; rt < 4; ++rt)
          acc[rt] = __builtin_amdgcn_mfma_f32_16x16x32_bf16(afrag[rt][kc], bf[kc], acc[rt], 0, 0, 0);
      const float wv = lds_w[ct * 16 + l16];
#pragma unroll
      for (int rt = 0; rt < 4; ++rt) {         // C/D: row=quad*4+reg, col=l16
        outacc[rt][0] += wv * __builtin_amdgcn_exp2f(acc[rt][0]);
        outacc[rt][1] += wv * __builtin_amdgcn_exp2f(acc[rt][1]);
        outacc[rt][2] += wv * __builtin_amdgcn_exp2f(acc[rt][2]);
        outacc[rt][3] += wv * __builtin_amdgcn_exp2f(acc[rt][3]);
      }
    }
    __syncthreads();   // publish this ss's writes; free read buffers
  }

  // reduce over the 16 columns (l16); fused reduce: atomicAdd into out
#pragma unroll
  for (int rt = 0; rt < 4; ++rt)
#pragma unroll
    for (int i = 0; i < 4; ++i) {
      float v = outacc[rt][i];
      v += __shfl_xor(v, 1, 64);
      v += __shfl_xor(v, 2, 64);
      v += __shfl_xor(v, 4, 64);
      v += __shfl_xor(v, 8, 64);
      if (l16 == 0) {
        const int row = my * 256 + wave * 64 + rt * 16 + quad * 4 + i;
        atomicAdd(&out[row], ea[row] * v);     // device-scope by default
      }
    }
}

extern "C" void kernel_launch(void* const* d_in, const int* in_sizes, int n_in,
                              void* d_out, int out_size, void* d_ws, size_t ws_size,
                              hipStream_t stream) {
  const float* Xq    = (const float*)d_in[0];
  const float* Xt    = (const float*)d_in[1];
  const float* alpha = (const float*)d_in[2];
  float* out = (float*)d_out;
  char*  ws  = (char*)d_ws;

  char*  Amat = ws + A_OFF;
  char*  Bmat = ws + B_OFF;
  float* w    = (float*)(ws + W_OFF);
  float* ea   = (float*)(ws + EA_OFF);

  hipLaunchKernelGGL(prep_kernel, dim3(256), dim3(256), 0, stream,
                     Xq, Xt, alpha, Amat, Bmat, w, ea, out);
  hipLaunchKernelGGL(rbf_main, dim3(512), dim3(256), 0, stream,
                     Amat, Bmat, w, ea, out);
}

// Round 7
// 129.536 us; speedup vs baseline: 1.0432x; 1.0432x over previous
//
#include <hip/hip_runtime.h>
#include <stdint.h>

// RBF kernel regression: out = exp(-gamma*d2(Xq,Xt)) @ alpha
// out[m] = ea[m] * sum_n w[n] * 2^( S[m][n] ),  S = (2*gamma*log2e*Xq).Xt^T
//
// R17: R0 main-loop structure EXACT (register ping-pong B, afrag resident,
// no main-loop barriers, NSPLIT=16, (256,2), R0 swizzle). LDS-B is dead:
// R11/R12/R13/R16 all showed hipcc targets the LDS-implied occupancy and
// either spills (R13: 266MB scratch) or rematerializes afrag loads into the
// loop (R16: VGPR=132, 75us) regardless of __launch_bounds__. Periphery
// optimizations only:
//  (a) A self-pack: rbf_main packs afrag straight from Xq fp32 in its
//      prologue (one-time) -> Amat and prep's A-half deleted, prep halved.
//  (b) ea computed in-prologue from the same fp32 reads (sumsq + 2 shfls),
//      stashed in 1KB LDS -> ea array deleted.
//  (c) reduce fused via atomicAdd (prep zeroes out) -> 3rd kernel deleted.
// R14 lesson: no s_setprio (splits sched regions -> regalloc damage).
// R1-R5 lesson: no global_load_lds (bypasses L2).

#define MM 8192
#define NN 8192
#define DD 256
#define GAMMA (1.0f/256.0f)
#define LOG2E 1.44269504088896340736f
#define SCALE_A (2.0f*GAMMA*LOG2E)
#define NEG_G_LOG2E (-GAMMA*LOG2E)

#define NSPLIT 16
#define NPB (NN/NSPLIT)     // 512 cols per block
#define NT_PER (NPB/16)     // 32 column-tiles of 16

typedef __bf16 bf16x8 __attribute__((ext_vector_type(8)));
typedef float  f32x4  __attribute__((ext_vector_type(4)));

// ws: [0,4MB) B frag-linear; [4MB,+32K) w
#define B_OFF  ((size_t)0)
#define W_OFF  ((size_t)4 << 20)

__device__ __forceinline__ unsigned short f2bf(float f) {  // RNE f32->bf16
  union { float f; uint32_t u; } x; x.f = f;
  uint32_t u = x.u;
  u += 0x7FFFu + ((u >> 16) & 1u);
  return (unsigned short)(u >> 16);
}
__device__ __forceinline__ uint32_t pack2(float a, float b) {
  return (uint32_t)f2bf(a) | ((uint32_t)f2bf(b) << 16);
}

// One wave per 16-col tile of B. Fragment-linear pack: tile t, round r,
// lane l writes Bmat + t*8192 + r*1024 + l*16 holding k-granule
// g=r*4+(l>>4) of col n=t*16+(l&15) — the mfma_16x16x32 B operand layout.
// Also computes w[n] = alpha[n]*exp(-gamma*||xt_n||^2) and zeroes out.
__global__ __launch_bounds__(256) void prep_kernel(
    const float* __restrict__ Xt, const float* __restrict__ alpha,
    char* __restrict__ Bmat, float* __restrict__ w, float* __restrict__ out)
{
  // zero the output (rbf_main accumulates into it with atomics)
  const int gi = blockIdx.x * 256 + threadIdx.x;
  if (gi < MM) out[gi] = 0.f;

  const int lane = threadIdx.x & 63;
  const int t = blockIdx.x * 4 + (threadIdx.x >> 6);   // 0..511
  const int n = t * 16 + (lane & 15);
  float ss = 0.f;
#pragma unroll
  for (int r = 0; r < 8; ++r) {
    const int gg = r * 4 + (lane >> 4);
    const float* p = Xt + (size_t)n * DD + gg * 8;
    const float4 f0 = *(const float4*)p;
    const float4 f1 = *(const float4*)(p + 4);
    ss += f0.x*f0.x + f0.y*f0.y + f0.z*f0.z + f0.w*f0.w
        + f1.x*f1.x + f1.y*f1.y + f1.z*f1.z + f1.w*f1.w;
    uint4 pk;
    pk.x = pack2(f0.x, f0.y); pk.y = pack2(f0.z, f0.w);
    pk.z = pack2(f1.x, f1.y); pk.w = pack2(f1.z, f1.w);
    *(uint4*)(Bmat + (size_t)t * 8192 + r * 1024 + lane * 16) = pk;
  }
  ss += __shfl_xor(ss, 16, 64);   // reduce the 4 lanes holding col n
  ss += __shfl_xor(ss, 32, 64);
  if (lane < 16) w[n] = alpha[n] * __builtin_amdgcn_exp2f(NEG_G_LOG2E * ss);
}

__global__ __launch_bounds__(256, 2) void rbf_main(
    const float* __restrict__ Xq, const char* __restrict__ Bmat,
    const float* __restrict__ w, float* __restrict__ out)
{
  __shared__ float lds_w[NPB];       // 2 KB: block's w slice
  __shared__ float lds_ea[4][64];    // 1 KB: per-wave row-scales ea
  const int tid  = threadIdx.x;
  const int wave = tid >> 6, lane = tid & 63;
  const int quad = lane >> 4, l16 = lane & 15;

  // R0 swizzle: 512 blocks = 32 my x 16 nx; XCD b&7 gets 8 my x 8 nx;
  // 8 consecutive slots share nx (B-panel locality in the XCD's L2).
  const int b    = blockIdx.x;
  const int xcd  = b & 7, slot = b >> 3;             // slot 0..63
  const int my   = (xcd & 3) * 8 + (slot & 7);       // 0..31 (256 rows each)
  const int nx   = (xcd >> 2) * 8 + (slot >> 3);     // 0..15
  const int mt0    = my * 16 + wave * 4;             // 4 mtiles = 64 rows/wave
  const int nt0    = nx * NT_PER;
  const int nbase0 = nx * NPB;

  // stage w slice to LDS (single barrier in the whole kernel)
  {
    const float2 wv2 = *(const float2*)(w + nbase0 + tid * 2);
    lds_w[tid * 2]     = wv2.x;
    lds_w[tid * 2 + 1] = wv2.y;
  }

  // A self-pack: fragments register-resident for full K=256 straight from
  // Xq fp32. Lane l holds row (mt0+rt)*16+l16, k-granule kc*4+quad (8 fp32
  // = 32B per (rt,kc)). Sum-of-squares rides along -> ea, no global array.
  float ssq[4] = {0.f, 0.f, 0.f, 0.f};
  bf16x8 afrag[4][8];
#pragma unroll
  for (int rt = 0; rt < 4; ++rt) {
    const float* rowp = Xq + (size_t)((mt0 + rt) * 16 + l16) * DD + quad * 8;
#pragma unroll
    for (int kc = 0; kc < 8; ++kc) {
      const float* p = rowp + kc * 32;       // granule kc*4+quad
      const float4 f0 = *(const float4*)p;
      const float4 f1 = *(const float4*)(p + 4);
      ssq[rt] += f0.x*f0.x + f0.y*f0.y + f0.z*f0.z + f0.w*f0.w
               + f1.x*f1.x + f1.y*f1.y + f1.z*f1.z + f1.w*f1.w;
      union { uint4 u; bf16x8 v; } cv;
      cv.u.x = pack2(f0.x*SCALE_A, f0.y*SCALE_A);
      cv.u.y = pack2(f0.z*SCALE_A, f0.w*SCALE_A);
      cv.u.z = pack2(f1.x*SCALE_A, f1.y*SCALE_A);
      cv.u.w = pack2(f1.z*SCALE_A, f1.w*SCALE_A);
      afrag[rt][kc] = cv.v;
    }
  }
#pragma unroll
  for (int rt = 0; rt < 4; ++rt) {           // full row sumsq across quads
    float s = ssq[rt];
    s += __shfl_xor(s, 16, 64);
    s += __shfl_xor(s, 32, 64);
    if (lane < 16)
      lds_ea[wave][rt * 16 + lane] = __builtin_amdgcn_exp2f(NEG_G_LOG2E * s);
  }

  __syncthreads();   // lds_w ready (lds_ea is wave-private)

  float outacc[4][4] = {{0,0,0,0},{0,0,0,0},{0,0,0,0},{0,0,0,0}};

  uint4 bufA[8], bufB[8];
  auto loadB = [&](uint4* dst, int ct) {
#pragma unroll
    for (int kc = 0; kc < 8; ++kc)
      dst[kc] = *(const uint4*)(Bmat + (size_t)(nt0 + ct) * 8192 + kc * 1024 + lane * 16);
  };

  const f32x4 fzero = {0.f, 0.f, 0.f, 0.f};
  f32x4 accA[4], accB[4];

  auto mfmaInto = [&](f32x4* acc, const uint4* buf) {
#pragma unroll
    for (int rt = 0; rt < 4; ++rt) acc[rt] = fzero;
#pragma unroll
    for (int kc = 0; kc < 8; ++kc) {
      union { uint4 u; bf16x8 v; } cv; cv.u = buf[kc];
#pragma unroll
      for (int rt = 0; rt < 4; ++rt)
        acc[rt] = __builtin_amdgcn_mfma_f32_16x16x32_bf16(afrag[rt][kc], cv.v, acc[rt], 0, 0, 0);
    }
  };
  auto epi = [&](const f32x4* acc, int ct) {
    const float wv = lds_w[ct * 16 + l16];   // ds_read: no vmcnt interaction
#pragma unroll
    for (int rt = 0; rt < 4; ++rt) {         // C/D: row=quad*4+reg, col=l16
      outacc[rt][0] += wv * __builtin_amdgcn_exp2f(acc[rt][0]);
      outacc[rt][1] += wv * __builtin_amdgcn_exp2f(acc[rt][1]);
      outacc[rt][2] += wv * __builtin_amdgcn_exp2f(acc[rt][2]);
      outacc[rt][3] += wv * __builtin_amdgcn_exp2f(acc[rt][3]);
    }
  };

  // software pipeline: epilogue of tile ct deferred under mfma of tile ct+1
  loadB(bufA, 0);
  loadB(bufB, 1);
  mfmaInto(accA, bufA);                    // tile 0
  for (int ct = 0; ct < NT_PER - 2; ct += 2) {
    loadB(bufA, ct + 2);                   // refill A-buf (tile ct just consumed)
    mfmaInto(accB, bufB);                  // tile ct+1
    epi(accA, ct);                         //   ...interleaves with the above
    loadB(bufB, ct + 3);
    mfmaInto(accA, bufA);                  // tile ct+2
    epi(accB, ct + 1);                     //   ...interleaves
  }
  mfmaInto(accB, bufB);                    // tile NT_PER-1
  epi(accA, NT_PER - 2);
  epi(accB, NT_PER - 1);

  // reduce over the 16 columns (l16); fused reduce: atomicAdd into out
#pragma unroll
  for (int rt = 0; rt < 4; ++rt)
#pragma unroll
    for (int i = 0; i < 4; ++i) {
      float v = outacc[rt][i];
      v += __shfl_xor(v, 1, 64);
      v += __shfl_xor(v, 2, 64);
      v += __shfl_xor(v, 4, 64);
      v += __shfl_xor(v, 8, 64);
      if (l16 == 0) {
        const int row = my * 256 + wave * 64 + rt * 16 + quad * 4 + i;
        atomicAdd(&out[row], lds_ea[wave][rt * 16 + quad * 4 + i] * v);
      }
    }
}

extern "C" void kernel_launch(void* const* d_in, const int* in_sizes, int n_in,
                              void* d_out, int out_size, void* d_ws, size_t ws_size,
                              hipStream_t stream) {
  const float* Xq    = (const float*)d_in[0];
  const float* Xt    = (const float*)d_in[1];
  const float* alpha = (const float*)d_in[2];
  float* out = (float*)d_out;
  char*  ws  = (char*)d_ws;

  char*  Bmat = ws + B_OFF;
  float* w    = (float*)(ws + W_OFF);

  hipLaunchKernelGGL(prep_kernel, dim3(128), dim3(256), 0, stream,
                     Xt, alpha, Bmat, w, out);
  hipLaunchKernelGGL(rbf_main, dim3(512), dim3(256), 0, stream,
                     Xq, Bmat, w, out);
}

// Round 8
// 100.672 us; speedup vs baseline: 1.3423x; 1.2867x over previous
//
#include <hip/hip_runtime.h>
#include <stdint.h>

// RBF kernel regression: out = exp(-gamma*d2(Xq,Xt)) @ alpha
// out[m] = ea[m] * sum_n w[n] * 2^( S[m][n] ),  S = (2*gamma*log2e*Xq).Xt^T
//
// R18: byte-exact R0 structure (prep packs Amat+Bmat frag-linear; rbf_main
// holds afrag resident via uint4 loads from Amat; register ping-pong B; no
// main-loop barriers; NSPLIT=16; (256,2); R0 swizzle), plus ONE periphery
// change: reduce kernel fused as atomicAdd epilogue (prep zeroes out).
//
// Session ledger (what is PROVEN on this problem):
//  - R11/R16: LDS-B multicast -> allocator targets LDS-implied occupancy,
//    remats afrag loads into the loop (VGPR 108/132), 59-75us.
//  - R12/R13/R17: launch_bounds(256,4)/(256,1)/fp32 self-pack -> 128-VGPR
//    cap + scratch spill (45-266MB fake traffic), 67-470us.
//  - R14: s_setprio splits sched regions -> same 128-cap spill, 94us.
//  - ONLY the R0 shape (uint4 Amat->afrag, ping-pong B) compiles clean.
//  - R15 (atomic fusion + pairing swizzle) = 103.6; this round isolates
//    whether the swizzle or the fusion caused the +4 vs R0's 99.4.
// R1-R5 lesson: no global_load_lds (bypasses L2, pins at 3TB/s).

#define MM 8192
#define NN 8192
#define DD 256
#define GAMMA (1.0f/256.0f)
#define LOG2E 1.44269504088896340736f
#define SCALE_A (2.0f*GAMMA*LOG2E)
#define NEG_G_LOG2E (-GAMMA*LOG2E)

#define NSPLIT 16
#define NPB (NN/NSPLIT)     // 512 cols per block
#define NT_PER (NPB/16)     // 32 column-tiles of 16

typedef __bf16 bf16x8 __attribute__((ext_vector_type(8)));
typedef float  f32x4  __attribute__((ext_vector_type(4)));

// ws: [0,4MB) A frag-linear; [4MB,8MB) B frag-linear; [8MB,+32K) w; [+32K] ea
#define A_OFF  ((size_t)0)
#define B_OFF  ((size_t)4 << 20)
#define W_OFF  ((size_t)8 << 20)
#define EA_OFF (((size_t)8 << 20) + 32768)

__device__ __forceinline__ unsigned short f2bf(float f) {  // RNE f32->bf16
  union { float f; uint32_t u; } x; x.f = f;
  uint32_t u = x.u;
  u += 0x7FFFu + ((u >> 16) & 1u);
  return (unsigned short)(u >> 16);
}
__device__ __forceinline__ uint32_t pack2(float a, float b) {
  return (uint32_t)f2bf(a) | ((uint32_t)f2bf(b) << 16);
}

// One wave per 16-row/col tile. Fragment-linear pack: tile t, round r, lane l
// writes dst + t*8192 + r*1024 + l*16 holding k-granule g=r*4+(l>>4) of
// row/col n=t*16+(l&15) — exactly the mfma_16x16x32 A/B operand layout.
__global__ __launch_bounds__(256) void prep_kernel(
    const float* __restrict__ Xq, const float* __restrict__ Xt,
    const float* __restrict__ alpha,
    char* __restrict__ Amat, char* __restrict__ Bmat,
    float* __restrict__ w, float* __restrict__ ea, float* __restrict__ out)
{
  // zero the output (rbf_main accumulates into it with atomics)
  const int gi = blockIdx.x * 256 + threadIdx.x;
  if (gi < MM) out[gi] = 0.f;

  const int lane = threadIdx.x & 63;
  const int gw = blockIdx.x * 4 + (threadIdx.x >> 6);  // 0..1023
  const bool isA = gw < 512;
  const int t = isA ? gw : gw - 512;
  const float* __restrict__ src = isA ? Xq : Xt;
  char* __restrict__ dst = isA ? Amat : Bmat;
  const float sc = isA ? SCALE_A : 1.0f;
  const int n = t * 16 + (lane & 15);
  float ss = 0.f;
#pragma unroll
  for (int r = 0; r < 8; ++r) {
    const int gg = r * 4 + (lane >> 4);
    const float* p = src + (size_t)n * DD + gg * 8;
    const float4 f0 = *(const float4*)p;
    const float4 f1 = *(const float4*)(p + 4);
    ss += f0.x*f0.x + f0.y*f0.y + f0.z*f0.z + f0.w*f0.w
        + f1.x*f1.x + f1.y*f1.y + f1.z*f1.z + f1.w*f1.w;
    uint4 pk;
    pk.x = pack2(f0.x * sc, f0.y * sc); pk.y = pack2(f0.z * sc, f0.w * sc);
    pk.z = pack2(f1.x * sc, f1.y * sc); pk.w = pack2(f1.z * sc, f1.w * sc);
    *(uint4*)(dst + (size_t)t * 8192 + r * 1024 + lane * 16) = pk;
  }
  ss += __shfl_xor(ss, 16, 64);   // reduce the 4 lanes holding col n
  ss += __shfl_xor(ss, 32, 64);
  if (lane < 16) {
    if (isA) ea[n] = __builtin_amdgcn_exp2f(NEG_G_LOG2E * ss);
    else     w[n]  = alpha[n] * __builtin_amdgcn_exp2f(NEG_G_LOG2E * ss);
  }
}

__global__ __launch_bounds__(256, 2) void rbf_main(
    const char* __restrict__ Amat, const char* __restrict__ Bmat,
    const float* __restrict__ w, const float* __restrict__ ea,
    float* __restrict__ out)
{
  __shared__ float lds_w[NPB];   // 2 KB: the block's w slice (lgkm-only reads)
  const int tid  = threadIdx.x;
  const int wave = tid >> 6, lane = tid & 63;
  const int quad = lane >> 4, l16 = lane & 15;

  // R0 swizzle: 512 blocks = 32 my x 16 nx; XCD b&7 gets 8 my x 8 nx;
  // 8 consecutive slots share nx (B-panel locality in the XCD's L2).
  const int b    = blockIdx.x;
  const int xcd  = b & 7, slot = b >> 3;             // slot 0..63
  const int my   = (xcd & 3) * 8 + (slot & 7);       // 0..31 (256 rows each)
  const int nx   = (xcd >> 2) * 8 + (slot >> 3);     // 0..15
  const int mt0    = my * 16 + wave * 4;             // 4 mtiles = 64 rows/wave
  const int nt0    = nx * NT_PER;
  const int nbase0 = nx * NPB;

  // stage w slice to LDS (single barrier in the whole kernel)
  {
    const float2 wv2 = *(const float2*)(w + nbase0 + tid * 2);
    lds_w[tid * 2]     = wv2.x;
    lds_w[tid * 2 + 1] = wv2.y;
  }

  // A fragments register-resident for full K=256: 4 mtiles x 8 kc = 128 VGPR
  bf16x8 afrag[4][8];
#pragma unroll
  for (int rt = 0; rt < 4; ++rt)
#pragma unroll
    for (int kc = 0; kc < 8; ++kc) {
      union { uint4 u; bf16x8 v; } cv;
      cv.u = *(const uint4*)(Amat + (size_t)(mt0 + rt) * 8192 + kc * 1024 + lane * 16);
      afrag[rt][kc] = cv.v;
    }

  __syncthreads();   // lds_w ready

  float outacc[4][4] = {{0,0,0,0},{0,0,0,0},{0,0,0,0},{0,0,0,0}};

  uint4 bufA[8], bufB[8];
  auto loadB = [&](uint4* dst, int ct) {
#pragma unroll
    for (int kc = 0; kc < 8; ++kc)
      dst[kc] = *(const uint4*)(Bmat + (size_t)(nt0 + ct) * 8192 + kc * 1024 + lane * 16);
  };

  const f32x4 fzero = {0.f, 0.f, 0.f, 0.f};
  f32x4 accA[4], accB[4];

  auto mfmaInto = [&](f32x4* acc, const uint4* buf) {
#pragma unroll
    for (int rt = 0; rt < 4; ++rt) acc[rt] = fzero;
#pragma unroll
    for (int kc = 0; kc < 8; ++kc) {
      union { uint4 u; bf16x8 v; } cv; cv.u = buf[kc];
#pragma unroll
      for (int rt = 0; rt < 4; ++rt)
        acc[rt] = __builtin_amdgcn_mfma_f32_16x16x32_bf16(afrag[rt][kc], cv.v, acc[rt], 0, 0, 0);
    }
  };
  auto epi = [&](const f32x4* acc, int ct) {
    const float wv = lds_w[ct * 16 + l16];   // ds_read: no vmcnt interaction
#pragma unroll
    for (int rt = 0; rt < 4; ++rt) {         // C/D: row=quad*4+reg, col=l16
      outacc[rt][0] += wv * __builtin_amdgcn_exp2f(acc[rt][0]);
      outacc[rt][1] += wv * __builtin_amdgcn_exp2f(acc[rt][1]);
      outacc[rt][2] += wv * __builtin_amdgcn_exp2f(acc[rt][2]);
      outacc[rt][3] += wv * __builtin_amdgcn_exp2f(acc[rt][3]);
    }
  };

  // software pipeline: epilogue of tile ct deferred under mfma of tile ct+1
  loadB(bufA, 0);
  loadB(bufB, 1);
  mfmaInto(accA, bufA);                    // tile 0
  for (int ct = 0; ct < NT_PER - 2; ct += 2) {
    loadB(bufA, ct + 2);                   // refill A-buf (tile ct just consumed)
    mfmaInto(accB, bufB);                  // tile ct+1
    epi(accA, ct);                         //   ...interleaves with the above
    loadB(bufB, ct + 3);
    mfmaInto(accA, bufA);                  // tile ct+2
    epi(accB, ct + 1);                     //   ...interleaves
  }
  mfmaInto(accB, bufB);                    // tile NT_PER-1
  epi(accA, NT_PER - 2);
  epi(accB, NT_PER - 1);

  // reduce over the 16 columns (l16); fused reduce: atomicAdd into out
#pragma unroll
  for (int rt = 0; rt < 4; ++rt)
#pragma unroll
    for (int i = 0; i < 4; ++i) {
      float v = outacc[rt][i];
      v += __shfl_xor(v, 1, 64);
      v += __shfl_xor(v, 2, 64);
      v += __shfl_xor(v, 4, 64);
      v += __shfl_xor(v, 8, 64);
      if (l16 == 0) {
        const int row = my * 256 + wave * 64 + rt * 16 + quad * 4 + i;
        atomicAdd(&out[row], ea[row] * v);   // device-scope by default
      }
    }
}

extern "C" void kernel_launch(void* const* d_in, const int* in_sizes, int n_in,
                              void* d_out, int out_size, void* d_ws, size_t ws_size,
                              hipStream_t stream) {
  const float* Xq    = (const float*)d_in[0];
  const float* Xt    = (const float*)d_in[1];
  const float* alpha = (const float*)d_in[2];
  float* out = (float*)d_out;
  char*  ws  = (char*)d_ws;

  char*  Amat = ws + A_OFF;
  char*  Bmat = ws + B_OFF;
  float* w    = (float*)(ws + W_OFF);
  float* ea   = (float*)(ws + EA_OFF);

  hipLaunchKernelGGL(prep_kernel, dim3(256), dim3(256), 0, stream,
                     Xq, Xt, alpha, Amat, Bmat, w, ea, out);
  hipLaunchKernelGGL(rbf_main, dim3(512), dim3(256), 0, stream,
                     Amat, Bmat, w, ea, out);
}